// Round 3
// baseline (229.946 us; speedup 1.0000x reference)
//
#include <hip/hip_runtime.h>
#include <hip/hip_bf16.h>

typedef __bf16 bf16x8 __attribute__((ext_vector_type(8)));
typedef float f32x4 __attribute__((ext_vector_type(4)));
typedef long longx2 __attribute__((ext_vector_type(2)));
typedef int i32x8 __attribute__((ext_vector_type(8)));

#define N 8192
#define D 512
#define NS 64

// workspace layout (bytes) — ~21 MB (unchanged)
#define XS_OFF 0                            // fp8 X [N][512 B] NATURAL k-order : 4 MB
#define WT_OFF (4 * 1024 * 1024)            // bf16 WT chunked [256][64s][32i] : 1 MB
#define SQ_OFF (WT_OFF + 1024 * 1024)       // f32 sq [N] : 32 KB
#define EP_OFF (SQ_OFF + 32 * 1024)         // f32 Ep [8 chunk][64 s][8192 n] : 16 MB
#define SC_OFF (EP_OFF + 8 * 64 * 8192 * 4) // f32 S1,S2 + int cnt

// raw barrier: drain LDS ops only; leave global loads (vmcnt) in flight.
#define BAR() do { asm volatile("s_waitcnt lgkmcnt(0)" ::: "memory"); \
                   __builtin_amdgcn_s_barrier(); } while (0)

// ---------------------------------------------------------------------------
// fused prep (blocks [0,2048): X -> fp8 natural order + sq; [2048,2176): W->WT)
__global__ __launch_bounds__(256) void prep(const float* __restrict__ X,
                                            const float* __restrict__ W,
                                            unsigned char* __restrict__ Xs,
                                            float* __restrict__ sq,
                                            __bf16* __restrict__ WTs,
                                            float* __restrict__ Sacc) {
    __shared__ float T[64][65];
    int t = threadIdx.x;
    if (blockIdx.x == 0 && t == 0) {        // zero loss accumulators + counter
        Sacc[0] = 0.f; Sacc[1] = 0.f; ((int*)Sacc)[2] = 0;
    }
    if (blockIdx.x < 2048) {
        int row = blockIdx.x * 4 + (t >> 6);
        int l = t & 63;
        const float* src = X + (size_t)row * D + l * 8;
        float4 v0 = *(const float4*)src;
        float4 v1 = *(const float4*)(src + 4);
        int w0 = __builtin_amdgcn_cvt_pk_fp8_f32(v0.x, v0.y, 0, false);
        w0     = __builtin_amdgcn_cvt_pk_fp8_f32(v0.z, v0.w, w0, true);
        int w1 = __builtin_amdgcn_cvt_pk_fp8_f32(v1.x, v1.y, 0, false);
        w1     = __builtin_amdgcn_cvt_pk_fp8_f32(v1.z, v1.w, w1, true);
        uint2 pk = make_uint2((unsigned)w0, (unsigned)w1);
        *(uint2*)(Xs + (size_t)row * 512 + l * 8) = pk;   // natural k order
        float acc = v0.x*v0.x + v0.y*v0.y + v0.z*v0.z + v0.w*v0.w
                  + v1.x*v1.x + v1.y*v1.y + v1.z*v1.z + v1.w*v1.w;
        for (int off = 32; off > 0; off >>= 1) acc += __shfl_down(acc, off);
        if (l == 0) sq[row] = acc;
    } else {
        int i0 = (blockIdx.x - 2048) * 64;
        for (int j = 0; j < 16; ++j) {
            int idx = t + 256 * j;
            T[idx & 63][idx >> 6] = W[(size_t)(i0 + (idx >> 6)) * NS + (idx & 63)];
        }
        __syncthreads();
        for (int h = 0; h < 2; ++h)
            for (int j = 0; j < 8; ++j) {
                int idx = t + 256 * j;                  // 0..2047
                int s = idx >> 5, il = idx & 31;
                WTs[(size_t)((i0 >> 5) + h) * 2048 + idx] = (__bf16)T[s][h * 32 + il];
            }
    }
}

// ---------------------------------------------------------------------------
// main, round-12 (MX, spill-free): grid (64 n-blocks, 8 i-chunks).
// r11 still spilled (WRITE 198 MB): E-phase arch demand ~138 > 128 split —
// the 32-reg pk array (exp results) carried across 3 barriers was the peak.
// This round: accG stays in AGPRs (96/128 used — free) until the KT-write
// phase; each wm-half computes d2->exp->bf16 AFTER its barrier and writes
// per-fragment immediately (transient ~12 regs). E-phase arch ~110-118.
//  - Gram via mfma_scale 16x16x128 (scale=1.0, bit-identical fp8, absmax=0
//    verified r10/r11). B kc128=0 in 32-reg VGPR cache bc; k 128..511 in
//    XOR-swizzled XnHi [3][128][128]; Xi [128][128] single-buffer unioned
//    with KT [128][72]; q-reg prefetch; raw s_barrier+lgkmcnt only.
__global__ __launch_bounds__(256, 2) void kpca_main(
        const unsigned char* __restrict__ Xs, const __bf16* __restrict__ WTs,
        const float* __restrict__ sq, float* __restrict__ Ep) {
    __shared__ __align__(16) unsigned char XiKT[18432];     // Xi[128][128] ∪ KT[128][72]bf16
    __shared__ __align__(16) unsigned char XnHi[3 * 16384]; // B-panel k 128..511, swizzled
    unsigned char* Xi = XiKT;
    __bf16* KT = (__bf16*)XiKT;

    const int t = threadIdx.x;
    const int w = t >> 6, l = t & 63;
    const int quad = l >> 4, l15 = l & 15;
    const int wm = w >> 1, wn = w & 1;
    const int n0 = blockIdx.x * 128;
    const int ic0 = blockIdx.y * 1024;

    union U8 { longx2 h[2]; i32x8 v; };

    // ---- prologue: B kc128=0 VGPR cache
    U8 bc[4];
    {
        const unsigned char* Bb = Xs + (size_t)(n0 + wn * 64 + l15) * 512 + quad * 32;
        #pragma unroll
        for (int nt = 0; nt < 4; ++nt) {
            bc[nt].h[0] = *(const longx2*)(Bb + nt * 8192);
            bc[nt].h[1] = *(const longx2*)(Bb + nt * 8192 + 16);
        }
    }
    // ---- prologue: XnHi [c][r][blk ^ (r&7)] for k-chunks 1..3
    #pragma unroll
    for (int m = 0; m < 12; ++m) {
        int id = m * 256 + t;                 // 0..3071
        int c = id >> 10, rem = id & 1023;
        int r = rem >> 3, j = rem & 7;
        uint4 v = *(const uint4*)(Xs + (size_t)(n0 + r) * 512 + 128 + c * 128 + j * 16);
        *(uint4*)(XnHi + c * 16384 + r * 128 + ((j ^ (r & 7)) << 4)) = v;
    }
    float sqn_v[4];
    #pragma unroll
    for (int nt = 0; nt < 4; ++nt)
        sqn_v[nt] = sq[n0 + wn * 64 + nt * 16 + l15];

    f32x4 accE[4][2];
    #pragma unroll
    for (int st = 0; st < 4; ++st)
        for (int n2 = 0; n2 < 2; ++n2)
            accE[st][n2] = (f32x4){0.f, 0.f, 0.f, 0.f};

    // staging geometry: 8 lanes cover one row's 128 B (16-B blocks, swizzled)
    const int rB = t >> 3;                 // 0..31 (row within 32-row group)
    const int cB = (t & 7) * 16;           // source 16-B column
    const int swoff = (((t & 7) ^ ((t >> 3) & 7)) << 4);   // write-side swizzle

    // fragment read offsets (swizzled 16-B block pair for k = quad*32..+32)
    const int oswL = (((2 * quad)     ^ (l15 & 7)) << 4);
    const int oswH = (((2 * quad + 1) ^ (l15 & 7)) << 4);

    // prestage chunk (it=0, ks=0)
    {
        const unsigned char* g = Xs + (size_t)(ic0 + rB) * 512 + cB;
        #pragma unroll
        for (int j = 0; j < 4; ++j)
            *(uint4*)(Xi + (size_t)(j * 32 + rB) * 128 + swoff) =
                *(const uint4*)(g + (size_t)j * 32 * 512);
    }

    uint4 q[4];   // prefetch regs, carried across the E phase at it boundaries

    for (int it = 0; it < 8; ++it) {
        const int i0 = ic0 + it * 128;
        f32x4 accG[4][4];
        #pragma unroll
        for (int mt = 0; mt < 4; ++mt)
            for (int nt = 0; nt < 4; ++nt)
                accG[mt][nt] = (f32x4){0.f, 0.f, 0.f, 0.f};

        if (it > 0) {
            BAR();   // E-phase KT reads done -> Xi region free
            #pragma unroll
            for (int j = 0; j < 4; ++j)
                *(uint4*)(Xi + (size_t)(j * 32 + rB) * 128 + swoff) = q[j];
        }

        #pragma unroll
        for (int ks = 0; ks < 4; ++ks) {
            const bool stage = (ks < 3) || (it < 7);
            if (stage) {
                const int itn = (ks < 3) ? it : it + 1;
                const int ksn = (ks + 1) & 3;
                const unsigned char* g =
                    Xs + (size_t)(ic0 + itn * 128 + rB) * 512 + ksn * 128 + cB;
                #pragma unroll
                for (int j = 0; j < 4; ++j)
                    q[j] = *(const uint4*)(g + (size_t)j * 32 * 512);
            }
            BAR();   // chunk ks stores visible

            U8 a[4];
            const unsigned char* abase = Xi + (wm * 64 + l15) * 128;
            #pragma unroll
            for (int mt = 0; mt < 4; ++mt) {
                a[mt].h[0] = *(const longx2*)(abase + mt * 2048 + oswL);
                a[mt].h[1] = *(const longx2*)(abase + mt * 2048 + oswH);
            }
            __builtin_amdgcn_s_setprio(1);
            if (ks == 0) {
                #pragma unroll
                for (int nt = 0; nt < 4; ++nt)
                    #pragma unroll
                    for (int mt = 0; mt < 4; ++mt)
                        accG[mt][nt] = __builtin_amdgcn_mfma_scale_f32_16x16x128_f8f6f4(
                            a[mt].v, bc[nt].v, accG[mt][nt],
                            0, 0, 0, 0x7F7F7F7F, 0, 0x7F7F7F7F);
            } else {
                const unsigned char* bbase =
                    XnHi + (ks - 1) * 16384 + (wn * 64 + l15) * 128;
                #pragma unroll
                for (int nt = 0; nt < 4; ++nt) {
                    U8 bb;   // streamed: one B-fragment live at a time
                    bb.h[0] = *(const longx2*)(bbase + nt * 2048 + oswL);
                    bb.h[1] = *(const longx2*)(bbase + nt * 2048 + oswH);
                    #pragma unroll
                    for (int mt = 0; mt < 4; ++mt)
                        accG[mt][nt] = __builtin_amdgcn_mfma_scale_f32_16x16x128_f8f6f4(
                            a[mt].v, bb.v, accG[mt][nt],
                            0, 0, 0, 0x7F7F7F7F, 0, 0x7F7F7F7F);
                }
            }
            __builtin_amdgcn_s_setprio(0);

            if (ks < 3) {
                BAR();   // all Xi reads of chunk ks done
                #pragma unroll
                for (int j = 0; j < 4; ++j)
                    *(uint4*)(Xi + (size_t)(j * 32 + rB) * 128 + swoff) = q[j];
            }
            // ks==3: q (next it's chunk 0) held in regs across the E phase
        }

        // ---- E phase. accG (AGPRs) carries the Gram tile; each wm-half
        // computes d2->exp->bf16 AFTER its barrier and writes immediately
        // (no 32-reg pk carried across barriers — r11's spill source).
        const __bf16* wslab = WTs + (size_t)(i0 >> 5) * 2048;

        auto write_pk = [&]() {
            #pragma unroll
            for (int mt = 0; mt < 4; ++mt) {
                f32x4 si = *(const f32x4*)(sq + i0 + wm * 64 + mt * 16 + quad * 4);
                #pragma unroll
                for (int nt = 0; nt < 4; ++nt) {
                    float sn = sqn_v[nt];
                    union { __bf16 h[4]; uint2 u; } u;
                    #pragma unroll
                    for (int r = 0; r < 4; ++r) {
                        float d2 = si[r] + sn - 2.0f * accG[mt][nt][r];
                        u.h[r] = (__bf16)__expf(d2 * -9.765625e-4f);  // exp(-d2/1024)
                    }
                    *(uint2*)(KT + (wn * 64 + nt * 16 + l15) * 72 + mt * 16 + quad * 4)
                        = u.u;
                }
            }
        };

        bf16x8 aw[2][4];
        #pragma unroll
        for (int kc2 = 0; kc2 < 2; ++kc2)
            for (int st = 0; st < 4; ++st)
                aw[kc2][st] = *(const bf16x8*)(wslab + kc2 * 2048 +
                                               (st * 16 + l15) * 32 + quad * 8);

        BAR();             // A: Gram Xi reads done -> KT region free
        if (wm == 0) write_pk();   // half 0: i-local 0..63
        BAR();             // B: KT half-0 visible
        #pragma unroll
        for (int kc2 = 0; kc2 < 2; ++kc2) {
            bf16x8 bk[2];
            for (int n2 = 0; n2 < 2; ++n2)
                bk[n2] = *(const bf16x8*)(KT + (w * 32 + n2 * 16 + l15) * 72 +
                                          kc2 * 32 + quad * 8);
            #pragma unroll
            for (int st = 0; st < 4; ++st)
                for (int n2 = 0; n2 < 2; ++n2)
                    accE[st][n2] = __builtin_amdgcn_mfma_f32_16x16x32_bf16(
                        aw[kc2][st], bk[n2], accE[st][n2], 0, 0, 0);
        }
        #pragma unroll
        for (int kc2 = 0; kc2 < 2; ++kc2)      // second half (kc2 2,3)
            for (int st = 0; st < 4; ++st)
                aw[kc2][st] = *(const bf16x8*)(wslab + (kc2 + 2) * 2048 +
                                               (st * 16 + l15) * 32 + quad * 8);
        BAR();             // C: half-0 E reads done
        if (wm == 1) write_pk();   // half 1: i-local 64..127
        BAR();             // D: KT half-1 visible
        #pragma unroll
        for (int kc2 = 0; kc2 < 2; ++kc2) {
            bf16x8 bk[2];
            for (int n2 = 0; n2 < 2; ++n2)
                bk[n2] = *(const bf16x8*)(KT + (w * 32 + n2 * 16 + l15) * 72 +
                                          kc2 * 32 + quad * 8);
            #pragma unroll
            for (int st = 0; st < 4; ++st)
                for (int n2 = 0; n2 < 2; ++n2)
                    accE[st][n2] = __builtin_amdgcn_mfma_f32_16x16x32_bf16(
                        aw[kc2][st], bk[n2], accE[st][n2], 0, 0, 0);
        }
    }

    // ---- per-chunk E partial: plain stores
    float* ep = Ep + (size_t)blockIdx.y * (NS * N);
    #pragma unroll
    for (int st = 0; st < 4; ++st)
        for (int n2 = 0; n2 < 2; ++n2)
            for (int r = 0; r < 4; ++r) {
                int s = st * 16 + quad * 4 + r;
                int n = n0 + w * 32 + n2 * 16 + l15;
                ep[(size_t)s * N + n] = accE[st][n2][r];
            }
}

// ---------------------------------------------------------------------------
// loss: 256 blocks = 64 s x 4 n-chunks; sums the 8 E partials, reduces;
// last block finalizes the scalar.
__global__ __launch_bounds__(256) void loss_kernel(const float* __restrict__ Ep,
                                                   const __bf16* __restrict__ WTs,
                                                   const float* __restrict__ lam,
                                                   float* __restrict__ Sacc,
                                                   float* __restrict__ out) {
    int s = blockIdx.x >> 2;
    int nb = (blockIdx.x & 3) * 2048;
    int t = threadIdx.x;
    float a1 = 0.f, a2 = 0.f;
    for (int j = 0; j < 8; ++j) {
        int n = nb + t + j * 256;
        float e = 0.f;
        #pragma unroll
        for (int c = 0; c < 8; ++c)
            e += Ep[(size_t)c * (NS * N) + (size_t)s * N + n];
        a1 += e * e;
        a2 += e * (float)WTs[(size_t)(n >> 5) * 2048 + s * 32 + (n & 31)];
    }
    for (int off = 32; off > 0; off >>= 1) {
        a1 += __shfl_down(a1, off);
        a2 += __shfl_down(a2, off);
    }
    __shared__ float r1[4], r2[4];
    int wv = t >> 6, ln = t & 63;
    if (ln == 0) { r1[wv] = a1; r2[wv] = a2; }
    __syncthreads();
    if (t == 0) {
        atomicAdd(Sacc + 0, lam[s] * (r1[0] + r1[1] + r1[2] + r1[3]));
        atomicAdd(Sacc + 1, r2[0] + r2[1] + r2[2] + r2[3]);
        __threadfence();
        int prev = atomicAdd((int*)Sacc + 2, 1);
        if (prev == 255) {                       // last block finalizes
            __threadfence();
            volatile float* vs = (volatile float*)Sacc;
            float L = 0.5f * (vs[1] - vs[0]);    // loss1=-S1/2, loss2=S2/2
            out[0] = L + 0.05f * L * L;          // C_STAB/2 = 0.05
        }
    }
}

// ---------------------------------------------------------------------------
extern "C" void kernel_launch(void* const* d_in, const int* in_sizes, int n_in,
                              void* d_out, int out_size, void* d_ws, size_t ws_size,
                              hipStream_t stream) {
    const float* X   = (const float*)d_in[0];   // [8192][512]
    const float* W   = (const float*)d_in[1];   // [8192][64]
    const float* lam = (const float*)d_in[2];   // [64]
    float* out = (float*)d_out;
    char* ws = (char*)d_ws;
    unsigned char* Xs = (unsigned char*)(ws + XS_OFF);
    __bf16* WTs = (__bf16*)(ws + WT_OFF);
    float* sq   = (float*)(ws + SQ_OFF);
    float* Ep   = (float*)(ws + EP_OFF);
    float* Sacc = (float*)(ws + SC_OFF);

    prep<<<2048 + 128, 256, 0, stream>>>(X, W, Xs, sq, WTs, Sacc);
    kpca_main<<<dim3(64, 8), 256, 0, stream>>>(Xs, WTs, sq, Ep);
    loss_kernel<<<256, 256, 0, stream>>>(Ep, WTs, lam, Sacc, out);
}

// Round 4
// 173.160 us; speedup vs baseline: 1.3279x; 1.3279x over previous
//
#include <hip/hip_runtime.h>
#include <hip/hip_bf16.h>

typedef __bf16 bf16x8 __attribute__((ext_vector_type(8)));
typedef float f32x4 __attribute__((ext_vector_type(4)));
typedef long longx2 __attribute__((ext_vector_type(2)));
typedef int i32x8 __attribute__((ext_vector_type(8)));

#define N 8192
#define D 512
#define NS 64

// workspace layout (bytes) — ~21 MB (unchanged)
#define XS_OFF 0                            // fp8 X [N][512 B] NATURAL k-order : 4 MB
#define WT_OFF (4 * 1024 * 1024)            // bf16 WT chunked [256][64s][32i] : 1 MB
#define SQ_OFF (WT_OFF + 1024 * 1024)       // f32 sq [N] : 32 KB
#define EP_OFF (SQ_OFF + 32 * 1024)         // f32 Ep [8 chunk][64 s][8192 n] : 16 MB
#define SC_OFF (EP_OFF + 8 * 64 * 8192 * 4) // f32 S1,S2 + int cnt

// raw barrier: drain LDS ops only; leave global loads (vmcnt) in flight.
#define BAR() do { asm volatile("s_waitcnt lgkmcnt(0)" ::: "memory"); \
                   __builtin_amdgcn_s_barrier(); } while (0)

// ---------------------------------------------------------------------------
// fused prep (blocks [0,2048): X -> fp8 natural order + sq; [2048,2176): W->WT)
__global__ __launch_bounds__(256) void prep(const float* __restrict__ X,
                                            const float* __restrict__ W,
                                            unsigned char* __restrict__ Xs,
                                            float* __restrict__ sq,
                                            __bf16* __restrict__ WTs,
                                            float* __restrict__ Sacc) {
    __shared__ float T[64][65];
    int t = threadIdx.x;
    if (blockIdx.x == 0 && t == 0) {        // zero loss accumulators + counter
        Sacc[0] = 0.f; Sacc[1] = 0.f; ((int*)Sacc)[2] = 0;
    }
    if (blockIdx.x < 2048) {
        int row = blockIdx.x * 4 + (t >> 6);
        int l = t & 63;
        const float* src = X + (size_t)row * D + l * 8;
        float4 v0 = *(const float4*)src;
        float4 v1 = *(const float4*)(src + 4);
        int w0 = __builtin_amdgcn_cvt_pk_fp8_f32(v0.x, v0.y, 0, false);
        w0     = __builtin_amdgcn_cvt_pk_fp8_f32(v0.z, v0.w, w0, true);
        int w1 = __builtin_amdgcn_cvt_pk_fp8_f32(v1.x, v1.y, 0, false);
        w1     = __builtin_amdgcn_cvt_pk_fp8_f32(v1.z, v1.w, w1, true);
        uint2 pk = make_uint2((unsigned)w0, (unsigned)w1);
        *(uint2*)(Xs + (size_t)row * 512 + l * 8) = pk;   // natural k order
        float acc = v0.x*v0.x + v0.y*v0.y + v0.z*v0.z + v0.w*v0.w
                  + v1.x*v1.x + v1.y*v1.y + v1.z*v1.z + v1.w*v1.w;
        for (int off = 32; off > 0; off >>= 1) acc += __shfl_down(acc, off);
        if (l == 0) sq[row] = acc;
    } else {
        int i0 = (blockIdx.x - 2048) * 64;
        for (int j = 0; j < 16; ++j) {
            int idx = t + 256 * j;
            T[idx & 63][idx >> 6] = W[(size_t)(i0 + (idx >> 6)) * NS + (idx & 63)];
        }
        __syncthreads();
        for (int h = 0; h < 2; ++h)
            for (int j = 0; j < 8; ++j) {
                int idx = t + 256 * j;                  // 0..2047
                int s = idx >> 5, il = idx & 31;
                WTs[(size_t)((i0 >> 5) + h) * 2048 + idx] = (__bf16)T[s][h * 32 + il];
            }
    }
}

// ---------------------------------------------------------------------------
// main, round-13 (MX, q-spill fix): grid (64 n-blocks, 8 i-chunks).
// r10-r12 all spilled ~1.3 KB/thread of scratch (WRITE 186-198 MB). Diagnosis:
// the 16-reg q[4] (next-it chunk-0 prefetch) was held across the E-phase
// register peak (aw 32 + bc 32 + transients) -> allocator spilled q every it.
// Fix: issue the chunk-0 loads AFTER barrier C (past the peak) — q is live
// only across the final bf16-MFMA cluster (~350 cy, covers the L3-resident
// Xs hit) and the it-top store. E peak ~107, Gram peak ~103, both < 128.
//  - Gram via mfma_scale 16x16x128 (scale=1.0, bit-identical fp8; absmax=0
//    verified r10-r12). B kc128=0 in 32-reg VGPR cache bc; k 128..511 in
//    XOR-swizzled XnHi [3][128][128]; Xi [128][128] unioned with KT [128][72];
//    raw s_barrier+lgkmcnt barriers keep global loads in flight.
__global__ __launch_bounds__(256, 2) void kpca_main(
        const unsigned char* __restrict__ Xs, const __bf16* __restrict__ WTs,
        const float* __restrict__ sq, float* __restrict__ Ep) {
    __shared__ __align__(16) unsigned char XiKT[18432];     // Xi[128][128] ∪ KT[128][72]bf16
    __shared__ __align__(16) unsigned char XnHi[3 * 16384]; // B-panel k 128..511, swizzled
    unsigned char* Xi = XiKT;
    __bf16* KT = (__bf16*)XiKT;

    const int t = threadIdx.x;
    const int w = t >> 6, l = t & 63;
    const int quad = l >> 4, l15 = l & 15;
    const int wm = w >> 1, wn = w & 1;
    const int n0 = blockIdx.x * 128;
    const int ic0 = blockIdx.y * 1024;

    union U8 { longx2 h[2]; i32x8 v; };

    // ---- prologue: B kc128=0 VGPR cache
    U8 bc[4];
    {
        const unsigned char* Bb = Xs + (size_t)(n0 + wn * 64 + l15) * 512 + quad * 32;
        #pragma unroll
        for (int nt = 0; nt < 4; ++nt) {
            bc[nt].h[0] = *(const longx2*)(Bb + nt * 8192);
            bc[nt].h[1] = *(const longx2*)(Bb + nt * 8192 + 16);
        }
    }
    // ---- prologue: XnHi [c][r][blk ^ (r&7)] for k-chunks 1..3
    #pragma unroll 4
    for (int m = 0; m < 12; ++m) {
        int id = m * 256 + t;                 // 0..3071
        int c = id >> 10, rem = id & 1023;
        int r = rem >> 3, j = rem & 7;
        uint4 v = *(const uint4*)(Xs + (size_t)(n0 + r) * 512 + 128 + c * 128 + j * 16);
        *(uint4*)(XnHi + c * 16384 + r * 128 + ((j ^ (r & 7)) << 4)) = v;
    }
    float sqn_v[4];
    #pragma unroll
    for (int nt = 0; nt < 4; ++nt)
        sqn_v[nt] = sq[n0 + wn * 64 + nt * 16 + l15];

    f32x4 accE[4][2];
    #pragma unroll
    for (int st = 0; st < 4; ++st)
        for (int n2 = 0; n2 < 2; ++n2)
            accE[st][n2] = (f32x4){0.f, 0.f, 0.f, 0.f};

    // staging geometry: 8 lanes cover one row's 128 B (16-B blocks, swizzled)
    const int rB = t >> 3;                 // 0..31 (row within 32-row group)
    const int cB = (t & 7) * 16;           // source 16-B column
    const int swoff = (((t & 7) ^ ((t >> 3) & 7)) << 4);   // write-side swizzle

    // fragment read offsets (swizzled 16-B block pair for k = quad*32..+32)
    const int oswL = (((2 * quad)     ^ (l15 & 7)) << 4);
    const int oswH = (((2 * quad + 1) ^ (l15 & 7)) << 4);

    // prestage chunk (it=0, ks=0)
    {
        const unsigned char* g = Xs + (size_t)(ic0 + rB) * 512 + cB;
        #pragma unroll
        for (int j = 0; j < 4; ++j)
            *(uint4*)(Xi + (size_t)(j * 32 + rB) * 128 + swoff) =
                *(const uint4*)(g + (size_t)j * 32 * 512);
    }

    uint4 q[4];   // prefetch regs; live only Gram-phase + E tail (post-C)

    for (int it = 0; it < 8; ++it) {
        const int i0 = ic0 + it * 128;
        f32x4 accG[4][4];
        #pragma unroll
        for (int mt = 0; mt < 4; ++mt)
            for (int nt = 0; nt < 4; ++nt)
                accG[mt][nt] = (f32x4){0.f, 0.f, 0.f, 0.f};

        if (it > 0) {
            BAR();   // E-phase KT reads done -> Xi region free
            #pragma unroll
            for (int j = 0; j < 4; ++j)   // q loaded post-barrier-C of prev it
                *(uint4*)(Xi + (size_t)(j * 32 + rB) * 128 + swoff) = q[j];
        }

        #pragma unroll
        for (int ks = 0; ks < 4; ++ks) {
            if (ks < 3) {   // prefetch this it's next chunk
                const unsigned char* g =
                    Xs + (size_t)(ic0 + it * 128 + rB) * 512 + (ks + 1) * 128 + cB;
                #pragma unroll
                for (int j = 0; j < 4; ++j)
                    q[j] = *(const uint4*)(g + (size_t)j * 32 * 512);
            }
            BAR();   // chunk ks stores visible

            U8 a[4];
            const unsigned char* abase = Xi + (wm * 64 + l15) * 128;
            #pragma unroll
            for (int mt = 0; mt < 4; ++mt) {
                a[mt].h[0] = *(const longx2*)(abase + mt * 2048 + oswL);
                a[mt].h[1] = *(const longx2*)(abase + mt * 2048 + oswH);
            }
            __builtin_amdgcn_s_setprio(1);
            if (ks == 0) {
                #pragma unroll
                for (int nt = 0; nt < 4; ++nt)
                    #pragma unroll
                    for (int mt = 0; mt < 4; ++mt)
                        accG[mt][nt] = __builtin_amdgcn_mfma_scale_f32_16x16x128_f8f6f4(
                            a[mt].v, bc[nt].v, accG[mt][nt],
                            0, 0, 0, 0x7F7F7F7F, 0, 0x7F7F7F7F);
            } else {
                const unsigned char* bbase =
                    XnHi + (ks - 1) * 16384 + (wn * 64 + l15) * 128;
                #pragma unroll
                for (int nt = 0; nt < 4; ++nt) {
                    U8 bb;   // streamed: one B-fragment live at a time
                    bb.h[0] = *(const longx2*)(bbase + nt * 2048 + oswL);
                    bb.h[1] = *(const longx2*)(bbase + nt * 2048 + oswH);
                    #pragma unroll
                    for (int mt = 0; mt < 4; ++mt)
                        accG[mt][nt] = __builtin_amdgcn_mfma_scale_f32_16x16x128_f8f6f4(
                            a[mt].v, bb.v, accG[mt][nt],
                            0, 0, 0, 0x7F7F7F7F, 0, 0x7F7F7F7F);
                }
            }
            __builtin_amdgcn_s_setprio(0);

            if (ks < 3) {
                BAR();   // all Xi reads of chunk ks done
                #pragma unroll
                for (int j = 0; j < 4; ++j)
                    *(uint4*)(Xi + (size_t)(j * 32 + rB) * 128 + swoff) = q[j];
            }
        }

        // ---- E phase. accG (AGPRs) carries the Gram tile; each wm-half
        // computes d2->exp->bf16 AFTER its barrier and writes immediately.
        const __bf16* wslab = WTs + (size_t)(i0 >> 5) * 2048;

        auto write_pk = [&]() {
            #pragma unroll
            for (int mt = 0; mt < 4; ++mt) {
                f32x4 si = *(const f32x4*)(sq + i0 + wm * 64 + mt * 16 + quad * 4);
                #pragma unroll
                for (int nt = 0; nt < 4; ++nt) {
                    float sn = sqn_v[nt];
                    union { __bf16 h[4]; uint2 u; } u;
                    #pragma unroll
                    for (int r = 0; r < 4; ++r) {
                        float d2 = si[r] + sn - 2.0f * accG[mt][nt][r];
                        u.h[r] = (__bf16)__expf(d2 * -9.765625e-4f);  // exp(-d2/1024)
                    }
                    *(uint2*)(KT + (wn * 64 + nt * 16 + l15) * 72 + mt * 16 + quad * 4)
                        = u.u;
                }
            }
        };

        bf16x8 aw[2][4];
        #pragma unroll
        for (int kc2 = 0; kc2 < 2; ++kc2)
            for (int st = 0; st < 4; ++st)
                aw[kc2][st] = *(const bf16x8*)(wslab + kc2 * 2048 +
                                               (st * 16 + l15) * 32 + quad * 8);

        BAR();             // A: Gram Xi reads done -> KT region free
        if (wm == 0) write_pk();   // half 0: i-local 0..63
        BAR();             // B: KT half-0 visible
        #pragma unroll
        for (int kc2 = 0; kc2 < 2; ++kc2) {
            bf16x8 bk[2];
            for (int n2 = 0; n2 < 2; ++n2)
                bk[n2] = *(const bf16x8*)(KT + (w * 32 + n2 * 16 + l15) * 72 +
                                          kc2 * 32 + quad * 8);
            #pragma unroll
            for (int st = 0; st < 4; ++st)
                for (int n2 = 0; n2 < 2; ++n2)
                    accE[st][n2] = __builtin_amdgcn_mfma_f32_16x16x32_bf16(
                        aw[kc2][st], bk[n2], accE[st][n2], 0, 0, 0);
        }
        #pragma unroll
        for (int kc2 = 0; kc2 < 2; ++kc2)      // second half (kc2 2,3)
            for (int st = 0; st < 4; ++st)
                aw[kc2][st] = *(const bf16x8*)(wslab + (kc2 + 2) * 2048 +
                                               (st * 16 + l15) * 32 + quad * 8);
        BAR();             // C: half-0 E reads done
        if (wm == 1) write_pk();   // half 1: i-local 64..127
        if (it < 7) {      // q prefetch for next it's chunk 0 — issued PAST the
                           // E-phase register peak; hidden under final MFMAs
            const unsigned char* g =
                Xs + (size_t)(ic0 + (it + 1) * 128 + rB) * 512 + cB;
            #pragma unroll
            for (int j = 0; j < 4; ++j)
                q[j] = *(const uint4*)(g + (size_t)j * 32 * 512);
        }
        BAR();             // D: KT half-1 visible
        #pragma unroll
        for (int kc2 = 0; kc2 < 2; ++kc2) {
            bf16x8 bk[2];
            for (int n2 = 0; n2 < 2; ++n2)
                bk[n2] = *(const bf16x8*)(KT + (w * 32 + n2 * 16 + l15) * 72 +
                                          kc2 * 32 + quad * 8);
            #pragma unroll
            for (int st = 0; st < 4; ++st)
                for (int n2 = 0; n2 < 2; ++n2)
                    accE[st][n2] = __builtin_amdgcn_mfma_f32_16x16x32_bf16(
                        aw[kc2][st], bk[n2], accE[st][n2], 0, 0, 0);
        }
    }

    // ---- per-chunk E partial: plain stores
    float* ep = Ep + (size_t)blockIdx.y * (NS * N);
    #pragma unroll
    for (int st = 0; st < 4; ++st)
        for (int n2 = 0; n2 < 2; ++n2)
            for (int r = 0; r < 4; ++r) {
                int s = st * 16 + quad * 4 + r;
                int n = n0 + w * 32 + n2 * 16 + l15;
                ep[(size_t)s * N + n] = accE[st][n2][r];
            }
}

// ---------------------------------------------------------------------------
// loss: 256 blocks = 64 s x 4 n-chunks; sums the 8 E partials, reduces;
// last block finalizes the scalar.
__global__ __launch_bounds__(256) void loss_kernel(const float* __restrict__ Ep,
                                                   const __bf16* __restrict__ WTs,
                                                   const float* __restrict__ lam,
                                                   float* __restrict__ Sacc,
                                                   float* __restrict__ out) {
    int s = blockIdx.x >> 2;
    int nb = (blockIdx.x & 3) * 2048;
    int t = threadIdx.x;
    float a1 = 0.f, a2 = 0.f;
    for (int j = 0; j < 8; ++j) {
        int n = nb + t + j * 256;
        float e = 0.f;
        #pragma unroll
        for (int c = 0; c < 8; ++c)
            e += Ep[(size_t)c * (NS * N) + (size_t)s * N + n];
        a1 += e * e;
        a2 += e * (float)WTs[(size_t)(n >> 5) * 2048 + s * 32 + (n & 31)];
    }
    for (int off = 32; off > 0; off >>= 1) {
        a1 += __shfl_down(a1, off);
        a2 += __shfl_down(a2, off);
    }
    __shared__ float r1[4], r2[4];
    int wv = t >> 6, ln = t & 63;
    if (ln == 0) { r1[wv] = a1; r2[wv] = a2; }
    __syncthreads();
    if (t == 0) {
        atomicAdd(Sacc + 0, lam[s] * (r1[0] + r1[1] + r1[2] + r1[3]));
        atomicAdd(Sacc + 1, r2[0] + r2[1] + r2[2] + r2[3]);
        __threadfence();
        int prev = atomicAdd((int*)Sacc + 2, 1);
        if (prev == 255) {                       // last block finalizes
            __threadfence();
            volatile float* vs = (volatile float*)Sacc;
            float L = 0.5f * (vs[1] - vs[0]);    // loss1=-S1/2, loss2=S2/2
            out[0] = L + 0.05f * L * L;          // C_STAB/2 = 0.05
        }
    }
}

// ---------------------------------------------------------------------------
extern "C" void kernel_launch(void* const* d_in, const int* in_sizes, int n_in,
                              void* d_out, int out_size, void* d_ws, size_t ws_size,
                              hipStream_t stream) {
    const float* X   = (const float*)d_in[0];   // [8192][512]
    const float* W   = (const float*)d_in[1];   // [8192][64]
    const float* lam = (const float*)d_in[2];   // [64]
    float* out = (float*)d_out;
    char* ws = (char*)d_ws;
    unsigned char* Xs = (unsigned char*)(ws + XS_OFF);
    __bf16* WTs = (__bf16*)(ws + WT_OFF);
    float* sq   = (float*)(ws + SQ_OFF);
    float* Ep   = (float*)(ws + EP_OFF);
    float* Sacc = (float*)(ws + SC_OFF);

    prep<<<2048 + 128, 256, 0, stream>>>(X, W, Xs, sq, WTs, Sacc);
    kpca_main<<<dim3(64, 8), 256, 0, stream>>>(Xs, WTs, sq, Ep);
    loss_kernel<<<256, 256, 0, stream>>>(Ep, WTs, lam, Sacc, out);
}

// Round 5
// 165.376 us; speedup vs baseline: 1.3904x; 1.0471x over previous
//
#include <hip/hip_runtime.h>
#include <hip/hip_bf16.h>

typedef __bf16 bf16x8 __attribute__((ext_vector_type(8)));
typedef float f32x4 __attribute__((ext_vector_type(4)));
typedef long longx2 __attribute__((ext_vector_type(2)));
typedef int i32x8 __attribute__((ext_vector_type(8)));

#define N 8192
#define D 512
#define NS 64

// workspace layout (bytes) — ~21 MB (unchanged)
#define XS_OFF 0                            // fp8 X [N][512 B] NATURAL k-order : 4 MB
#define WT_OFF (4 * 1024 * 1024)            // bf16 WT chunked [256][64s][32i] : 1 MB
#define SQ_OFF (WT_OFF + 1024 * 1024)       // f32 sq [N] : 32 KB
#define EP_OFF (SQ_OFF + 32 * 1024)         // f32 Ep [8 chunk][64 s][8192 n] : 16 MB
#define SC_OFF (EP_OFF + 8 * 64 * 8192 * 4) // f32 S1,S2 + int cnt

// raw barrier: drain LDS ops only; leave global loads (vmcnt) in flight.
#define BAR() do { asm volatile("s_waitcnt lgkmcnt(0)" ::: "memory"); \
                   __builtin_amdgcn_s_barrier(); } while (0)

// ---------------------------------------------------------------------------
// fused prep (blocks [0,2048): X -> fp8 natural order + sq; [2048,2176): W->WT)
__global__ __launch_bounds__(256) void prep(const float* __restrict__ X,
                                            const float* __restrict__ W,
                                            unsigned char* __restrict__ Xs,
                                            float* __restrict__ sq,
                                            __bf16* __restrict__ WTs,
                                            float* __restrict__ Sacc) {
    __shared__ float T[64][65];
    int t = threadIdx.x;
    if (blockIdx.x == 0 && t == 0) {        // zero loss accumulators + counter
        Sacc[0] = 0.f; Sacc[1] = 0.f; ((int*)Sacc)[2] = 0;
    }
    if (blockIdx.x < 2048) {
        int row = blockIdx.x * 4 + (t >> 6);
        int l = t & 63;
        const float* src = X + (size_t)row * D + l * 8;
        float4 v0 = *(const float4*)src;
        float4 v1 = *(const float4*)(src + 4);
        int w0 = __builtin_amdgcn_cvt_pk_fp8_f32(v0.x, v0.y, 0, false);
        w0     = __builtin_amdgcn_cvt_pk_fp8_f32(v0.z, v0.w, w0, true);
        int w1 = __builtin_amdgcn_cvt_pk_fp8_f32(v1.x, v1.y, 0, false);
        w1     = __builtin_amdgcn_cvt_pk_fp8_f32(v1.z, v1.w, w1, true);
        uint2 pk = make_uint2((unsigned)w0, (unsigned)w1);
        *(uint2*)(Xs + (size_t)row * 512 + l * 8) = pk;   // natural k order
        float acc = v0.x*v0.x + v0.y*v0.y + v0.z*v0.z + v0.w*v0.w
                  + v1.x*v1.x + v1.y*v1.y + v1.z*v1.z + v1.w*v1.w;
        for (int off = 32; off > 0; off >>= 1) acc += __shfl_down(acc, off);
        if (l == 0) sq[row] = acc;
    } else {
        int i0 = (blockIdx.x - 2048) * 64;
        for (int j = 0; j < 16; ++j) {
            int idx = t + 256 * j;
            T[idx & 63][idx >> 6] = W[(size_t)(i0 + (idx >> 6)) * NS + (idx & 63)];
        }
        __syncthreads();
        for (int h = 0; h < 2; ++h)
            for (int j = 0; j < 8; ++j) {
                int idx = t + 256 * j;                  // 0..2047
                int s = idx >> 5, il = idx & 31;
                WTs[(size_t)((i0 >> 5) + h) * 2048 + idx] = (__bf16)T[s][h * 32 + il];
            }
    }
}

// ---------------------------------------------------------------------------
// main, round-14 (MX, all-B-in-LDS): grid (64 n-blocks, 8 i-chunks).
// r13 confirmed the q-spill mechanism (WRITE 188->85 MB) but ~16 dw/it of
// spill remain — the static reg model is ~16 optimistic at the E peak.
// Decisive cut: drop the 32-reg bc cache entirely. All 4 B k-chunks live in
// XOR-swizzled XnHi [4][128][128] (64 KB). KT shrinks [128][72]->[128][64]
// XOR-swizzled (conflict-free by bank arithmetic: b128 reads 8 words/bank,
// b64 writes 4 words/bank — both minimum), so Xi[128][128] ∪ KT = 16 KB and
// LDS totals exactly 81920 B -> still 2 blocks/CU (2x80 KB = all 160 KB).
// Gram arch peak ~85, E peak ~90: 30+ regs of slack vs the model error.
//  - Gram via mfma_scale 16x16x128 (scale=1.0, bit-identical fp8; absmax=0
//    r10-r13). q prefetch timed past the E peak (r13). Raw s_barrier+lgkmcnt
//    barriers keep global loads in flight.
// Tripwire (pre-committed): WRITE>50MB or main>76us -> revert to r0 kernel.
__global__ __launch_bounds__(256, 2) void kpca_main(
        const unsigned char* __restrict__ Xs, const __bf16* __restrict__ WTs,
        const float* __restrict__ sq, float* __restrict__ Ep) {
    __shared__ __align__(16) unsigned char XiKT[16384];     // Xi[128][128] ∪ KT[128][64]bf16 (swz)
    __shared__ __align__(16) unsigned char XnHi[4 * 16384]; // B-panel k 0..511, swizzled
    unsigned char* Xi = XiKT;

    const int t = threadIdx.x;
    const int w = t >> 6, l = t & 63;
    const int quad = l >> 4, l15 = l & 15;
    const int wm = w >> 1, wn = w & 1;
    const int n0 = blockIdx.x * 128;
    const int ic0 = blockIdx.y * 1024;
    const int sw7 = l15 & 7;               // row&7 for all fragment rows

    union U8 { longx2 h[2]; i32x8 v; };

    // ---- prologue: XnHi [c][r][blk ^ (r&7)] for k-chunks 0..3 (all of B)
    #pragma unroll 4
    for (int m = 0; m < 16; ++m) {
        int id = m * 256 + t;                 // 0..4095
        int c = id >> 10, rem = id & 1023;
        int r = rem >> 3, j = rem & 7;
        uint4 v = *(const uint4*)(Xs + (size_t)(n0 + r) * 512 + c * 128 + j * 16);
        *(uint4*)(XnHi + c * 16384 + r * 128 + ((j ^ (r & 7)) << 4)) = v;
    }
    float sqn_v[4];
    #pragma unroll
    for (int nt = 0; nt < 4; ++nt)
        sqn_v[nt] = sq[n0 + wn * 64 + nt * 16 + l15];

    f32x4 accE[4][2];
    #pragma unroll
    for (int st = 0; st < 4; ++st)
        for (int n2 = 0; n2 < 2; ++n2)
            accE[st][n2] = (f32x4){0.f, 0.f, 0.f, 0.f};

    // staging geometry: 8 lanes cover one row's 128 B (16-B blocks, swizzled)
    const int rB = t >> 3;                 // 0..31 (row within 32-row group)
    const int cB = (t & 7) * 16;           // source 16-B column
    const int swoff = (((t & 7) ^ ((t >> 3) & 7)) << 4);   // write-side swizzle

    // fragment read offsets (swizzled 16-B block pair for k = quad*32..+32)
    const int oswL = (((2 * quad)     ^ sw7) << 4);
    const int oswH = (((2 * quad + 1) ^ sw7) << 4);

    // prestage chunk (it=0, ks=0)
    {
        const unsigned char* g = Xs + (size_t)(ic0 + rB) * 512 + cB;
        #pragma unroll
        for (int j = 0; j < 4; ++j)
            *(uint4*)(Xi + (size_t)(j * 32 + rB) * 128 + swoff) =
                *(const uint4*)(g + (size_t)j * 32 * 512);
    }

    uint4 q[4];   // prefetch regs; live only Gram-phase + E tail (post-C)

    for (int it = 0; it < 8; ++it) {
        const int i0 = ic0 + it * 128;
        f32x4 accG[4][4];
        #pragma unroll
        for (int mt = 0; mt < 4; ++mt)
            for (int nt = 0; nt < 4; ++nt)
                accG[mt][nt] = (f32x4){0.f, 0.f, 0.f, 0.f};

        if (it > 0) {
            BAR();   // E-phase KT reads done -> Xi region free
            #pragma unroll
            for (int j = 0; j < 4; ++j)   // q loaded post-barrier-C of prev it
                *(uint4*)(Xi + (size_t)(j * 32 + rB) * 128 + swoff) = q[j];
        }

        #pragma unroll
        for (int ks = 0; ks < 4; ++ks) {
            if (ks < 3) {   // prefetch this it's next chunk
                const unsigned char* g =
                    Xs + (size_t)(ic0 + it * 128 + rB) * 512 + (ks + 1) * 128 + cB;
                #pragma unroll
                for (int j = 0; j < 4; ++j)
                    q[j] = *(const uint4*)(g + (size_t)j * 32 * 512);
            }
            BAR();   // chunk ks stores visible

            U8 a[4];
            const unsigned char* abase = Xi + (wm * 64 + l15) * 128;
            #pragma unroll
            for (int mt = 0; mt < 4; ++mt) {
                a[mt].h[0] = *(const longx2*)(abase + mt * 2048 + oswL);
                a[mt].h[1] = *(const longx2*)(abase + mt * 2048 + oswH);
            }
            const unsigned char* bbase = XnHi + ks * 16384 + (wn * 64 + l15) * 128;
            __builtin_amdgcn_s_setprio(1);
            #pragma unroll
            for (int nt = 0; nt < 4; ++nt) {
                U8 bb;   // streamed: one B-fragment live at a time
                bb.h[0] = *(const longx2*)(bbase + nt * 2048 + oswL);
                bb.h[1] = *(const longx2*)(bbase + nt * 2048 + oswH);
                #pragma unroll
                for (int mt = 0; mt < 4; ++mt)
                    accG[mt][nt] = __builtin_amdgcn_mfma_scale_f32_16x16x128_f8f6f4(
                        a[mt].v, bb.v, accG[mt][nt],
                        0, 0, 0, 0x7F7F7F7F, 0, 0x7F7F7F7F);
            }
            __builtin_amdgcn_s_setprio(0);

            if (ks < 3) {
                BAR();   // all Xi reads of chunk ks done
                #pragma unroll
                for (int j = 0; j < 4; ++j)
                    *(uint4*)(Xi + (size_t)(j * 32 + rB) * 128 + swoff) = q[j];
            }
        }

        // ---- E phase. accG (AGPRs) carries the Gram tile; each wm-half
        // computes d2->exp->bf16 AFTER its barrier and writes immediately.
        // KT is [128][64] bf16 with 16-B-block XOR swizzle (blk ^= row&7).
        const __bf16* wslab = WTs + (size_t)(i0 >> 5) * 2048;

        auto write_pk = [&]() {
            #pragma unroll
            for (int mt = 0; mt < 4; ++mt) {
                f32x4 si = *(const f32x4*)(sq + i0 + wm * 64 + mt * 16 + quad * 4);
                #pragma unroll
                for (int nt = 0; nt < 4; ++nt) {
                    float sn = sqn_v[nt];
                    union { __bf16 h[4]; uint2 u; } u;
                    #pragma unroll
                    for (int r = 0; r < 4; ++r) {
                        float d2 = si[r] + sn - 2.0f * accG[mt][nt][r];
                        u.h[r] = (__bf16)__expf(d2 * -9.765625e-4f);  // exp(-d2/1024)
                    }
                    int row = wn * 64 + nt * 16 + l15;
                    int blk = mt * 2 + (quad >> 1);
                    *(uint2*)(XiKT + row * 128 + ((blk ^ sw7) << 4) + (quad & 1) * 8)
                        = u.u;
                }
            }
        };

        bf16x8 aw[2][4];
        #pragma unroll
        for (int kc2 = 0; kc2 < 2; ++kc2)
            for (int st = 0; st < 4; ++st)
                aw[kc2][st] = *(const bf16x8*)(wslab + kc2 * 2048 +
                                               (st * 16 + l15) * 32 + quad * 8);

        BAR();             // A: Gram Xi reads done -> KT region free
        if (wm == 0) write_pk();   // half 0: i-local 0..63
        BAR();             // B: KT half-0 visible
        #pragma unroll
        for (int kc2 = 0; kc2 < 2; ++kc2) {
            bf16x8 bk[2];
            for (int n2 = 0; n2 < 2; ++n2) {
                int row = w * 32 + n2 * 16 + l15;
                bk[n2] = *(const bf16x8*)(XiKT + row * 128 +
                                          (((kc2 * 4 + quad) ^ sw7) << 4));
            }
            #pragma unroll
            for (int st = 0; st < 4; ++st)
                for (int n2 = 0; n2 < 2; ++n2)
                    accE[st][n2] = __builtin_amdgcn_mfma_f32_16x16x32_bf16(
                        aw[kc2][st], bk[n2], accE[st][n2], 0, 0, 0);
        }
        #pragma unroll
        for (int kc2 = 0; kc2 < 2; ++kc2)      // second half (kc2 2,3)
            for (int st = 0; st < 4; ++st)
                aw[kc2][st] = *(const bf16x8*)(wslab + (kc2 + 2) * 2048 +
                                               (st * 16 + l15) * 32 + quad * 8);
        BAR();             // C: half-0 E reads done
        if (wm == 1) write_pk();   // half 1: i-local 64..127
        if (it < 7) {      // q prefetch for next it's chunk 0 — issued PAST the
                           // E-phase register peak; hidden under final MFMAs
            const unsigned char* g =
                Xs + (size_t)(ic0 + (it + 1) * 128 + rB) * 512 + cB;
            #pragma unroll
            for (int j = 0; j < 4; ++j)
                q[j] = *(const uint4*)(g + (size_t)j * 32 * 512);
        }
        BAR();             // D: KT half-1 visible
        #pragma unroll
        for (int kc2 = 0; kc2 < 2; ++kc2) {
            bf16x8 bk[2];
            for (int n2 = 0; n2 < 2; ++n2) {
                int row = w * 32 + n2 * 16 + l15;
                bk[n2] = *(const bf16x8*)(XiKT + row * 128 +
                                          (((kc2 * 4 + quad) ^ sw7) << 4));
            }
            #pragma unroll
            for (int st = 0; st < 4; ++st)
                for (int n2 = 0; n2 < 2; ++n2)
                    accE[st][n2] = __builtin_amdgcn_mfma_f32_16x16x32_bf16(
                        aw[kc2][st], bk[n2], accE[st][n2], 0, 0, 0);
        }
    }

    // ---- per-chunk E partial: plain stores
    float* ep = Ep + (size_t)blockIdx.y * (NS * N);
    #pragma unroll
    for (int st = 0; st < 4; ++st)
        for (int n2 = 0; n2 < 2; ++n2)
            for (int r = 0; r < 4; ++r) {
                int s = st * 16 + quad * 4 + r;
                int n = n0 + w * 32 + n2 * 16 + l15;
                ep[(size_t)s * N + n] = accE[st][n2][r];
            }
}

// ---------------------------------------------------------------------------
// loss: 256 blocks = 64 s x 4 n-chunks; sums the 8 E partials, reduces;
// last block finalizes the scalar.
__global__ __launch_bounds__(256) void loss_kernel(const float* __restrict__ Ep,
                                                   const __bf16* __restrict__ WTs,
                                                   const float* __restrict__ lam,
                                                   float* __restrict__ Sacc,
                                                   float* __restrict__ out) {
    int s = blockIdx.x >> 2;
    int nb = (blockIdx.x & 3) * 2048;
    int t = threadIdx.x;
    float a1 = 0.f, a2 = 0.f;
    for (int j = 0; j < 8; ++j) {
        int n = nb + t + j * 256;
        float e = 0.f;
        #pragma unroll
        for (int c = 0; c < 8; ++c)
            e += Ep[(size_t)c * (NS * N) + (size_t)s * N + n];
        a1 += e * e;
        a2 += e * (float)WTs[(size_t)(n >> 5) * 2048 + s * 32 + (n & 31)];
    }
    for (int off = 32; off > 0; off >>= 1) {
        a1 += __shfl_down(a1, off);
        a2 += __shfl_down(a2, off);
    }
    __shared__ float r1[4], r2[4];
    int wv = t >> 6, ln = t & 63;
    if (ln == 0) { r1[wv] = a1; r2[wv] = a2; }
    __syncthreads();
    if (t == 0) {
        atomicAdd(Sacc + 0, lam[s] * (r1[0] + r1[1] + r1[2] + r1[3]));
        atomicAdd(Sacc + 1, r2[0] + r2[1] + r2[2] + r2[3]);
        __threadfence();
        int prev = atomicAdd((int*)Sacc + 2, 1);
        if (prev == 255) {                       // last block finalizes
            __threadfence();
            volatile float* vs = (volatile float*)Sacc;
            float L = 0.5f * (vs[1] - vs[0]);    // loss1=-S1/2, loss2=S2/2
            out[0] = L + 0.05f * L * L;          // C_STAB/2 = 0.05
        }
    }
}

// ---------------------------------------------------------------------------
extern "C" void kernel_launch(void* const* d_in, const int* in_sizes, int n_in,
                              void* d_out, int out_size, void* d_ws, size_t ws_size,
                              hipStream_t stream) {
    const float* X   = (const float*)d_in[0];   // [8192][512]
    const float* W   = (const float*)d_in[1];   // [8192][64]
    const float* lam = (const float*)d_in[2];   // [64]
    float* out = (float*)d_out;
    char* ws = (char*)d_ws;
    unsigned char* Xs = (unsigned char*)(ws + XS_OFF);
    __bf16* WTs = (__bf16*)(ws + WT_OFF);
    float* sq   = (float*)(ws + SQ_OFF);
    float* Ep   = (float*)(ws + EP_OFF);
    float* Sacc = (float*)(ws + SC_OFF);

    prep<<<2048 + 128, 256, 0, stream>>>(X, W, Xs, sq, WTs, Sacc);
    kpca_main<<<dim3(64, 8), 256, 0, stream>>>(Xs, WTs, sq, Ep);
    loss_kernel<<<256, 256, 0, stream>>>(Ep, WTs, lam, Sacc, out);
}

// Round 6
// 146.899 us; speedup vs baseline: 1.5653x; 1.1258x over previous
//
#include <hip/hip_runtime.h>
#include <hip/hip_bf16.h>

typedef __bf16 bf16x8 __attribute__((ext_vector_type(8)));
typedef float f32x4 __attribute__((ext_vector_type(4)));
typedef long longx2 __attribute__((ext_vector_type(2)));

#define N 8192
#define D 512
#define NS 64

// workspace layout (bytes) — ~21 MB
#define XS_OFF 0                            // fp8 X [N][512 B] k-permuted : 4 MB
#define WT_OFF (4 * 1024 * 1024)            // bf16 WT chunked [256][64s][32i] : 1 MB
#define SQ_OFF (WT_OFF + 1024 * 1024)       // f32 sq [N] : 32 KB
#define EP_OFF (SQ_OFF + 32 * 1024)         // f32 Ep [8 chunk][64 s][8192 n] : 16 MB
#define SC_OFF (EP_OFF + 8 * 64 * 8192 * 4) // f32 S1,S2 + int cnt

// raw barrier: drain LDS ops only; leave global loads (vmcnt) in flight.
// __syncthreads() emits s_waitcnt vmcnt(0) before s_barrier, forcing each
// wave to wait for its own qA/qB prefetch AT the barrier — defeating the
// issued-a-kc8-ahead pattern. All cross-wave hand-offs here are LDS, so
// lgkmcnt(0)+s_barrier is sufficient (r10-r14: absmax 0.0 with this BAR).
#define BAR() do { asm volatile("s_waitcnt lgkmcnt(0)" ::: "memory"); \
                   __builtin_amdgcn_s_barrier(); } while (0)

// ---------------------------------------------------------------------------
// fused prep (blocks [0,2048): X -> fp8 k-permuted + sq; [2048,2176): W -> WT)
// Per 64-B k-group of X, 16-B block q holds [k=q*8..+8 | k=32+q*8..+8] so one
// 16-B read = both K32-half fragments for MFMA lane quad=q.
__global__ __launch_bounds__(256) void prep(const float* __restrict__ X,
                                            const float* __restrict__ W,
                                            unsigned char* __restrict__ Xs,
                                            float* __restrict__ sq,
                                            __bf16* __restrict__ WTs,
                                            float* __restrict__ Sacc) {
    __shared__ float T[64][65];
    int t = threadIdx.x;
    if (blockIdx.x == 0 && t == 0) {        // zero loss accumulators + counter
        Sacc[0] = 0.f; Sacc[1] = 0.f; ((int*)Sacc)[2] = 0;
    }
    if (blockIdx.x < 2048) {
        int row = blockIdx.x * 4 + (t >> 6);
        int l = t & 63;
        const float* src = X + (size_t)row * D + l * 8;
        float4 v0 = *(const float4*)src;
        float4 v1 = *(const float4*)(src + 4);
        int w0 = __builtin_amdgcn_cvt_pk_fp8_f32(v0.x, v0.y, 0, false);
        w0     = __builtin_amdgcn_cvt_pk_fp8_f32(v0.z, v0.w, w0, true);
        int w1 = __builtin_amdgcn_cvt_pk_fp8_f32(v1.x, v1.y, 0, false);
        w1     = __builtin_amdgcn_cvt_pk_fp8_f32(v1.z, v1.w, w1, true);
        int g = l >> 3, kh = (l >> 2) & 1, q = l & 3;
        int pos = g * 64 + q * 16 + kh * 8;
        uint2 pk = make_uint2((unsigned)w0, (unsigned)w1);
        *(uint2*)(Xs + (size_t)row * 512 + pos) = pk;
        float acc = v0.x*v0.x + v0.y*v0.y + v0.z*v0.z + v0.w*v0.w
                  + v1.x*v1.x + v1.y*v1.y + v1.z*v1.z + v1.w*v1.w;
        for (int off = 32; off > 0; off >>= 1) acc += __shfl_down(acc, off);
        if (l == 0) sq[row] = acc;
    } else {
        int i0 = (blockIdx.x - 2048) * 64;
        for (int j = 0; j < 16; ++j) {
            int idx = t + 256 * j;
            T[idx & 63][idx >> 6] = W[(size_t)(i0 + (idx >> 6)) * NS + (idx & 63)];
        }
        __syncthreads();
        for (int h = 0; h < 2; ++h)
            for (int j = 0; j < 8; ++j) {
                int idx = t + 256 * j;                  // 0..2047
                int s = idx >> 5, il = idx & 31;
                WTs[(size_t)((i0 >> 5) + h) * 2048 + idx] = (__bf16)T[s][h * 32 + il];
            }
    }
}

// ---------------------------------------------------------------------------
// main (round-5 measured optimum + BAR): grid (64 n-blocks, 8 i-chunks).
// Per block, 8 its of 128 i:
//  - Gram 128x128 fp8 16x16x32, Xi double-buffered (1 barrier/kc8, loads
//    issued a full kc8 ahead); B-frags kc8 0..3 from VGPR cache bc (64 regs),
//    kc8 4..7 from persistent padded LDS panel XnHi.
//  - exp epilogue -> KT bf16 halves [128][72]; E-phase 16x16x32 bf16 with
//    WT frags direct from global in two 32-reg halves (no spill).
//  - E partials per i-chunk, plain stores (no memset, no atomics).
// r15 change vs r0: all 5 block barriers are BAR() (lgkmcnt-only) so the
// kc8-ahead global prefetch stays in flight across the barrier; its vmcnt
// wait moves to the ds_write after the MFMA phase (T4 mechanism).
// Walls (measured r4-r9): arch-VGPR cap 128 (MX/bigger caches spill);
// frag-direct global loads uncoalesced; LDS <= 80K for 2 blocks/CU;
// E-phase must be bf16 (fp8 KT fails absmax). MX path falsified r10-r14:
// needs single-buffered Xi (2 barriers/chunk, 18% MfmaUtil) or 1 blk/CU.
__global__ __launch_bounds__(256, 2) void kpca_main(
        const unsigned char* __restrict__ Xs, const __bf16* __restrict__ WTs,
        const float* __restrict__ sq, float* __restrict__ Ep) {
    __shared__ __align__(16) unsigned char Xi[2][8192];       // [128][64] dbuf
    __shared__ __align__(16) unsigned char XnHi[128 * 272];   // 256 B data + 16 pad
    __shared__ __align__(16) __bf16 KT[128 * 72];             // [n][72] (64 i + 8 pad)

    const int t = threadIdx.x;
    const int w = t >> 6, l = t & 63;
    const int quad = l >> 4, l15 = l & 15;
    const int wm = w >> 1, wn = w & 1;
    const int n0 = blockIdx.x * 128;
    const int ic0 = blockIdx.y * 1024;

    // ---- prologue: B-frag VGPR cache (kc8 0..3) + persistent XnHi (kc8 4..7)
    longx2 bc[4][4];
    {
        const unsigned char* Bb = Xs + (size_t)(n0 + wn * 64 + l15) * 512 + quad * 16;
        #pragma unroll
        for (int k8 = 0; k8 < 4; ++k8)
            #pragma unroll
            for (int nt = 0; nt < 4; ++nt)
                bc[k8][nt] = *(const longx2*)(Bb + nt * (16 * 512) + k8 * 64);
    }
    {
        int r = t >> 1, h = t & 1;
        const unsigned char* g = Xs + (size_t)(n0 + r) * 512 + 256 + h * 128;
        unsigned char* d = XnHi + r * 272 + h * 128;
        #pragma unroll
        for (int j = 0; j < 8; ++j)
            *(uint4*)(d + j * 16) = *(const uint4*)(g + j * 16);
    }
    float sqn_v[4];
    for (int nt = 0; nt < 4; ++nt)
        sqn_v[nt] = sq[n0 + wn * 64 + nt * 16 + l15];

    f32x4 accE[4][2];
    for (int st = 0; st < 4; ++st)
        for (int n2 = 0; n2 < 2; ++n2)
            accE[st][n2] = (f32x4){0.f, 0.f, 0.f, 0.f};

    // staging geometry: thread stages 2 x 16 B (rows 0..63 and 64..127)
    const int ra = t >> 2, blk = (t & 3) * 16;

    // preload tile (it=0, kc8=0) into buf0
    {
        const unsigned char* g = Xs + (size_t)(ic0 + ra) * 512 + blk;
        *(uint4*)(Xi[0] + t * 16)        = *(const uint4*)g;
        *(uint4*)(Xi[0] + t * 16 + 4096) = *(const uint4*)(g + 64 * 512);
    }

    for (int it = 0; it < 8; ++it) {
        const int i0 = ic0 + it * 128;
        f32x4 accG[4][4];
        for (int mt = 0; mt < 4; ++mt)
            for (int nt = 0; nt < 4; ++nt)
                accG[mt][nt] = (f32x4){0.f, 0.f, 0.f, 0.f};

        #pragma unroll
        for (int kc8 = 0; kc8 < 8; ++kc8) {
            // prefetch next tile (full kc8-step of latency hiding)
            uint4 qA, qB;
            const bool stage = (kc8 < 7) || (it < 7);
            if (stage) {
                const int kn = (kc8 + 1) & 7;
                const int i0n = i0 + ((kc8 == 7) ? 128 : 0);
                const unsigned char* g = Xs + (size_t)(i0n + ra) * 512 + kn * 64 + blk;
                qA = *(const uint4*)g;
                qB = *(const uint4*)(g + 64 * 512);
            }
            BAR();   // buf[kc8&1] stores visible; prior reads of other buf done
                     // (global prefetch qA/qB stays in flight across this)
            const unsigned char* xb = Xi[kc8 & 1];
            longx2 a[4], b[4];
            #pragma unroll
            for (int mt = 0; mt < 4; ++mt)
                a[mt] = *(const longx2*)(xb + (wm * 64 + mt * 16 + l15) * 64 + quad * 16);
            if (kc8 < 4) {
                #pragma unroll
                for (int nt = 0; nt < 4; ++nt) b[nt] = bc[kc8][nt];
            } else {
                #pragma unroll
                for (int nt = 0; nt < 4; ++nt)
                    b[nt] = *(const longx2*)(XnHi + (wn * 64 + nt * 16 + l15) * 272 +
                                             (kc8 - 4) * 64 + quad * 16);
            }
            #pragma unroll
            for (int mt = 0; mt < 4; ++mt)
                #pragma unroll
                for (int nt = 0; nt < 4; ++nt)
                    accG[mt][nt] = __builtin_amdgcn_mfma_f32_16x16x32_fp8_fp8(
                        a[mt][0], b[nt][0], accG[mt][nt], 0, 0, 0);
            #pragma unroll
            for (int mt = 0; mt < 4; ++mt)
                #pragma unroll
                for (int nt = 0; nt < 4; ++nt)
                    accG[mt][nt] = __builtin_amdgcn_mfma_f32_16x16x32_fp8_fp8(
                        a[mt][1], b[nt][1], accG[mt][nt], 0, 0, 0);
            if (stage) {
                unsigned char* xd = Xi[(kc8 + 1) & 1];
                *(uint4*)(xd + t * 16)        = qA;   // vmcnt wait lands here,
                *(uint4*)(xd + t * 16 + 4096) = qB;   // after the MFMA phase
            }
        }

        // ---- epilogue: d2 -> exp -> packed bf16 (accG dies here)
        uint2 pk[4][4];
        #pragma unroll
        for (int mt = 0; mt < 4; ++mt) {
            f32x4 si = *(const f32x4*)(sq + i0 + wm * 64 + mt * 16 + quad * 4);
            #pragma unroll
            for (int nt = 0; nt < 4; ++nt) {
                float sn = sqn_v[nt];
                union { __bf16 h[4]; uint2 u; } u;
                #pragma unroll
                for (int r = 0; r < 4; ++r) {
                    float d2 = si[r] + sn - 2.0f * accG[mt][nt][r];
                    u.h[r] = (__bf16)__expf(d2 * -9.765625e-4f);   // exp(-d2/1024)
                }
                pk[mt][nt] = u.u;
            }
        }

        const __bf16* wslab = WTs + (size_t)(i0 >> 5) * 2048;
        bf16x8 aw[2][4];
        #pragma unroll
        for (int kc2 = 0; kc2 < 2; ++kc2)
            for (int st = 0; st < 4; ++st)
                aw[kc2][st] = *(const bf16x8*)(wslab + kc2 * 2048 +
                                               (st * 16 + l15) * 32 + quad * 8);

        BAR();             // A: prev it's E-phase KT reads done
        if (wm == 0) {     // half 0: i-local 0..63 (C layout col=l15(n), row=quad*4+r)
            #pragma unroll
            for (int mt = 0; mt < 4; ++mt)
                for (int nt = 0; nt < 4; ++nt)
                    *(uint2*)(KT + (wn * 64 + nt * 16 + l15) * 72 + mt * 16 + quad * 4)
                        = pk[mt][nt];
        }
        BAR();             // B: KT half-0 visible
        #pragma unroll
        for (int kc2 = 0; kc2 < 2; ++kc2) {
            bf16x8 bk[2];
            for (int n2 = 0; n2 < 2; ++n2)
                bk[n2] = *(const bf16x8*)(KT + (w * 32 + n2 * 16 + l15) * 72 +
                                          kc2 * 32 + quad * 8);
            #pragma unroll
            for (int st = 0; st < 4; ++st)
                for (int n2 = 0; n2 < 2; ++n2)
                    accE[st][n2] = __builtin_amdgcn_mfma_f32_16x16x32_bf16(
                        aw[kc2][st], bk[n2], accE[st][n2], 0, 0, 0);
        }
        #pragma unroll
        for (int kc2 = 0; kc2 < 2; ++kc2)      // second half (kc2 2,3)
            for (int st = 0; st < 4; ++st)
                aw[kc2][st] = *(const bf16x8*)(wslab + (kc2 + 2) * 2048 +
                                               (st * 16 + l15) * 32 + quad * 8);
        BAR();             // C: half-0 E reads done
        if (wm == 1) {     // half 1: i-local 64..127
            #pragma unroll
            for (int mt = 0; mt < 4; ++mt)
                for (int nt = 0; nt < 4; ++nt)
                    *(uint2*)(KT + (wn * 64 + nt * 16 + l15) * 72 + mt * 16 + quad * 4)
                        = pk[mt][nt];
        }
        BAR();             // D: KT half-1 visible
        #pragma unroll
        for (int kc2 = 0; kc2 < 2; ++kc2) {
            bf16x8 bk[2];
            for (int n2 = 0; n2 < 2; ++n2)
                bk[n2] = *(const bf16x8*)(KT + (w * 32 + n2 * 16 + l15) * 72 +
                                          kc2 * 32 + quad * 8);
            #pragma unroll
            for (int st = 0; st < 4; ++st)
                for (int n2 = 0; n2 < 2; ++n2)
                    accE[st][n2] = __builtin_amdgcn_mfma_f32_16x16x32_bf16(
                        aw[kc2][st], bk[n2], accE[st][n2], 0, 0, 0);
        }
    }

    // ---- per-chunk E partial: plain stores
    float* ep = Ep + (size_t)blockIdx.y * (NS * N);
    #pragma unroll
    for (int st = 0; st < 4; ++st)
        for (int n2 = 0; n2 < 2; ++n2)
            for (int r = 0; r < 4; ++r) {
                int s = st * 16 + quad * 4 + r;
                int n = n0 + w * 32 + n2 * 16 + l15;
                ep[(size_t)s * N + n] = accE[st][n2][r];
            }
}

// ---------------------------------------------------------------------------
// loss: 256 blocks = 64 s x 4 n-chunks; sums the 8 E partials, reduces;
// last block finalizes the scalar.
__global__ __launch_bounds__(256) void loss_kernel(const float* __restrict__ Ep,
                                                   const __bf16* __restrict__ WTs,
                                                   const float* __restrict__ lam,
                                                   float* __restrict__ Sacc,
                                                   float* __restrict__ out) {
    int s = blockIdx.x >> 2;
    int nb = (blockIdx.x & 3) * 2048;
    int t = threadIdx.x;
    float a1 = 0.f, a2 = 0.f;
    for (int j = 0; j < 8; ++j) {
        int n = nb + t + j * 256;
        float e = 0.f;
        #pragma unroll
        for (int c = 0; c < 8; ++c)
            e += Ep[(size_t)c * (NS * N) + (size_t)s * N + n];
        a1 += e * e;
        a2 += e * (float)WTs[(size_t)(n >> 5) * 2048 + s * 32 + (n & 31)];
    }
    for (int off = 32; off > 0; off >>= 1) {
        a1 += __shfl_down(a1, off);
        a2 += __shfl_down(a2, off);
    }
    __shared__ float r1[4], r2[4];
    int wv = t >> 6, ln = t & 63;
    if (ln == 0) { r1[wv] = a1; r2[wv] = a2; }
    __syncthreads();
    if (t == 0) {
        atomicAdd(Sacc + 0, lam[s] * (r1[0] + r1[1] + r1[2] + r1[3]));
        atomicAdd(Sacc + 1, r2[0] + r2[1] + r2[2] + r2[3]);
        __threadfence();
        int prev = atomicAdd((int*)Sacc + 2, 1);
        if (prev == 255) {                       // last block finalizes
            __threadfence();
            volatile float* vs = (volatile float*)Sacc;
            float L = 0.5f * (vs[1] - vs[0]);    // loss1=-S1/2, loss2=S2/2
            out[0] = L + 0.05f * L * L;          // C_STAB/2 = 0.05
        }
    }
}

// ---------------------------------------------------------------------------
extern "C" void kernel_launch(void* const* d_in, const int* in_sizes, int n_in,
                              void* d_out, int out_size, void* d_ws, size_t ws_size,
                              hipStream_t stream) {
    const float* X   = (const float*)d_in[0];   // [8192][512]
    const float* W   = (const float*)d_in[1];   // [8192][64]
    const float* lam = (const float*)d_in[2];   // [64]
    float* out = (float*)d_out;
    char* ws = (char*)d_ws;
    unsigned char* Xs = (unsigned char*)(ws + XS_OFF);
    __bf16* WTs = (__bf16*)(ws + WT_OFF);
    float* sq   = (float*)(ws + SQ_OFF);
    float* Ep   = (float*)(ws + EP_OFF);
    float* Sacc = (float*)(ws + SC_OFF);

    prep<<<2048 + 128, 256, 0, stream>>>(X, W, Xs, sq, WTs, Sacc);
    kpca_main<<<dim3(64, 8), 256, 0, stream>>>(Xs, WTs, sq, Ep);
    loss_kernel<<<256, 256, 0, stream>>>(Ep, WTs, lam, Sacc, out);
}